// Round 2
// baseline (955.900 us; speedup 1.0000x reference)
//
#include <hip/hip_runtime.h>
#include <stdint.h>

// Problem constants
constexpr int B_ = 8, N_ = 4096, E_ = 2048, C_ = 128;
constexpr int CN = 144;   // 128 channels + 1 ones-col + 15 pad
constexpr int KT = 32;    // K per MFMA step
constexpr int MT = 64;    // M rows per block (4 x 16-row groups, all owned by every wave)
constexpr int NWK = 4;    // K-split across the 4 waves of a block
constexpr int LRF = 145;  // reduction LDS row stride (floats)

typedef short bf16x8 __attribute__((ext_vector_type(8)));
typedef float f32x4  __attribute__((ext_vector_type(4)));

__device__ inline uint16_t bf16_rne(float f) {
    uint32_t u = __builtin_bit_cast(uint32_t, f);
    return (uint16_t)((u + 0x7FFFu + ((u >> 16) & 1u)) >> 16);
}

constexpr size_t HT_E  = (size_t)B_ * (N_ / 32) * E_;  // 2M dwords = 8 MB
constexpr size_t WT_E  = (size_t)CN * C_;
constexpr size_t EBF_E = (size_t)B_ * CN * E_;

// ---------------------------------------------------------------------------
// pack: H (fp32 0/1) -> HT[b][n/32][e], bit i of word = H[b][32*(n/32)+i][e].
// ---------------------------------------------------------------------------
__global__ void pack_kernel(const float* __restrict__ H, uint32_t* __restrict__ HT) {
    const int t  = threadIdx.x;
    const int eg = blockIdx.x & 7;
    const int ng = (blockIdx.x >> 3) & 127;
    const int b  = blockIdx.x >> 10;
    const int e  = eg * 256 + t;
    const float* hp = H + ((size_t)b * N_ + ng * 32) * E_ + e;
    uint32_t w = 0;
#pragma unroll
    for (int i = 0; i < 32; ++i) w |= (hp[(size_t)i * E_] > 0.5f) ? (1u << i) : 0u;
    HT[((size_t)b * (N_ / 32) + ng) * E_ + e] = w;
}

// ---------------------------------------------------------------------------
// prep: WTb = bf16(W^T) padded to 144 rows; constant rows 128..143 of xwbT
// (in d_out) and ebfT (ws): row 128 = 1.0 (ones-col -> s_e / d_n), rest 0.
// ---------------------------------------------------------------------------
__global__ void prep_kernel(const float* __restrict__ W, uint16_t* __restrict__ WTb,
                            uint32_t* __restrict__ xwbT32, uint32_t* __restrict__ ebfT32) {
    const int NW = (int)WT_E;                  // 18432
    const int NX = B_ * 16 * (N_ / 2);         // 262144 dwords
    const int NE = B_ * 16 * (E_ / 2);         // 131072 dwords
    int stride = gridDim.x * blockDim.x;
    for (int i = blockIdx.x * blockDim.x + threadIdx.x; i < NW + NX + NE; i += stride) {
        if (i < NW) {
            int c = i >> 7, k = i & 127;
            WTb[i] = bf16_rne((c < C_) ? W[k * C_ + c] : 0.f);
        } else if (i < NW + NX) {
            int j = i - NW;
            int b = j >> 15, rr = j & 32767;
            int r = rr >> 11, n2 = rr & 2047;
            xwbT32[((size_t)b * CN + (C_ + r)) * (N_ / 2) + n2] = (r == 0) ? 0x3F803F80u : 0u;
        } else {
            int j = i - NW - NX;
            int b = j >> 14, rr = j & 16383;
            int r = rr >> 10, e2 = rr & 1023;
            ebfT32[((size_t)b * CN + (C_ + r)) * (E_ / 2) + e2] = (r == 0) ? 0x3F803F80u : 0u;
        }
    }
}

// ---------------------------------------------------------------------------
// Barrier-free MFMA GEMM, MT=64 (round-0 structure) + REP diagnostic loop.
// REP>1 repeats the full (idempotent) computation inside one dispatch so the
// dispatch exceeds the harness poison-fills and surfaces in the top-5 counter
// table with representative MfmaUtil/VALUBusy/FETCH_SIZE.
//  MODE 0 (fc) : A = x fp32,    B = WTb,  out bf16 C^T xwbT (+bias)
//  MODE 1 (v2e): A = H^T bits,  B = xwbT, out bf16 C^T ebfT (x 1/s_e)
//  MODE 2 (e2v): A = H bits,    B = ebfT, out fp32 row-major (x 1/d_n)
// ---------------------------------------------------------------------------
template <int MODE, int REP>
__global__ __launch_bounds__(256, 2)
void gemm_k(const float* __restrict__ Ax, const uint32_t* __restrict__ HT,
            const uint16_t* __restrict__ Btb, const float* __restrict__ bias,
            uint16_t* __restrict__ outT, float* __restrict__ outF) {
    constexpr int K  = (MODE == 0) ? C_ : (MODE == 1) ? N_ : E_;
    constexpr int KW = K / NWK;                 // per-wave K chunk
    constexpr int SW = KW / KT;                 // 1 / 32 / 16 iterations
    constexpr size_t BBS = (MODE == 0) ? 0 : (size_t)CN * K;
    constexpr int OLD = (MODE == 0) ? N_ : E_;

    __shared__ float R[2 * 64 * LRF];           // two 64x144 reduction regions (74 KB)

    const int t = threadIdx.x, wave = t >> 6, lane = t & 63;
    const int l15 = lane & 15, quad = lane >> 4;
    const int batch = blockIdx.x & 7;           // XCD spread: panels stay in one L2
    const int m0 = (blockIdx.x >> 3) * MT;
    const int kwv = wave * KW;

    const uint16_t* Bp = Btb + (size_t)batch * BBS;
    const uint32_t* Hp = HT + (size_t)batch * (N_ / 32) * E_;

#pragma unroll 1
    for (int rep = 0; rep < REP; ++rep) {
        asm volatile("" ::: "memory");          // block cross-rep CSE of loads

        f32x4 acc[36];
#pragma unroll
        for (int i = 0; i < 36; ++i) acc[i] = (f32x4){0.f, 0.f, 0.f, 0.f};

        // single-buffered A state; double-buffered B (literal indices only)
        float    af[32];                // MODE 0: 4 groups x 8
        uint32_t aw[4];                 // MODE 1: one word per 16-row group
        uint4    axl[2], axh[2];        // MODE 2: two n-word-rows x 8 e-words
        bf16x8   bf0[9], bf1[9];

        auto loadA = [&](int k0) __attribute__((always_inline)) {
            if constexpr (MODE == 0) {
#pragma unroll
                for (int g = 0; g < 4; ++g) {
                    const float* ap = Ax + ((size_t)batch * N_ + m0 + g * 16 + l15) * C_ + k0 + quad * 8;
                    const float4 f0 = *(const float4*)ap;
                    const float4 f1 = *(const float4*)(ap + 4);
                    af[g * 8 + 0] = f0.x; af[g * 8 + 1] = f0.y; af[g * 8 + 2] = f0.z; af[g * 8 + 3] = f0.w;
                    af[g * 8 + 4] = f1.x; af[g * 8 + 5] = f1.y; af[g * 8 + 6] = f1.z; af[g * 8 + 7] = f1.w;
                }
            } else if constexpr (MODE == 1) {
                const uint32_t* p = Hp + (size_t)(k0 >> 5) * E_ + m0 + l15;
                aw[0] = p[0]; aw[1] = p[16]; aw[2] = p[32]; aw[3] = p[48];
            } else {
                const uint32_t* p = Hp + (size_t)(m0 >> 5) * E_ + k0 + quad * 8;
                axl[0] = *(const uint4*)p;        axh[0] = *(const uint4*)(p + 4);
                axl[1] = *(const uint4*)(p + E_); axh[1] = *(const uint4*)(p + E_ + 4);
            }
        };
        auto loadB = [&](int k0, int buf) __attribute__((always_inline)) {
            bf16x8* dst = buf ? bf1 : bf0;
#pragma unroll
            for (int j = 0; j < 9; ++j)
                dst[j] = *(const bf16x8*)&Bp[(size_t)(j * 16 + l15) * K + k0 + quad * 8];
        };
        auto mkfrag = [&](int g) __attribute__((always_inline)) -> bf16x8 {
            bf16x8 v;
            if constexpr (MODE == 0) {
#pragma unroll
                for (int jj = 0; jj < 8; ++jj) v[jj] = (short)bf16_rne(af[g * 8 + jj]);
            } else if constexpr (MODE == 1) {
                const uint32_t w = aw[g];
                const int base = quad * 8;
#pragma unroll
                for (int jj = 0; jj < 8; ++jj)
                    v[jj] = (short)(((w >> (base + jj)) & 1u) ? 0x3F80 : 0);
            } else {
                const int row = g >> 1, bit = (g & 1) * 16 + l15;
                const uint32_t u[8] = {axl[row].x, axl[row].y, axl[row].z, axl[row].w,
                                       axh[row].x, axh[row].y, axh[row].z, axh[row].w};
#pragma unroll
                for (int jj = 0; jj < 8; ++jj)
                    v[jj] = (short)(((u[jj] >> bit) & 1u) ? 0x3F80 : 0);
            }
            return v;
        };

        loadA(kwv); loadB(kwv, 0);
#pragma unroll 1
        for (int s = 0; s < SW; s += 2) {
            if (s + 1 < SW) loadB(kwv + (s + 1) * KT, 1);
            {
                bf16x8 a0 = mkfrag(0), a1 = mkfrag(1), a2 = mkfrag(2), a3 = mkfrag(3);
                if (s + 1 < SW) loadA(kwv + (s + 1) * KT);   // A regs free after frag build
#pragma unroll
                for (int j = 0; j < 9; ++j) {
                    acc[j]      = __builtin_amdgcn_mfma_f32_16x16x32_bf16(a0, bf0[j], acc[j],      0, 0, 0);
                    acc[9 + j]  = __builtin_amdgcn_mfma_f32_16x16x32_bf16(a1, bf0[j], acc[9 + j],  0, 0, 0);
                    acc[18 + j] = __builtin_amdgcn_mfma_f32_16x16x32_bf16(a2, bf0[j], acc[18 + j], 0, 0, 0);
                    acc[27 + j] = __builtin_amdgcn_mfma_f32_16x16x32_bf16(a3, bf0[j], acc[27 + j], 0, 0, 0);
                }
            }
            if (s + 1 < SW) {
                if (s + 2 < SW) loadB(kwv + (s + 2) * KT, 0);
                bf16x8 a0 = mkfrag(0), a1 = mkfrag(1), a2 = mkfrag(2), a3 = mkfrag(3);
                if (s + 2 < SW) loadA(kwv + (s + 2) * KT);
#pragma unroll
                for (int j = 0; j < 9; ++j) {
                    acc[j]      = __builtin_amdgcn_mfma_f32_16x16x32_bf16(a0, bf1[j], acc[j],      0, 0, 0);
                    acc[9 + j]  = __builtin_amdgcn_mfma_f32_16x16x32_bf16(a1, bf1[j], acc[9 + j],  0, 0, 0);
                    acc[18 + j] = __builtin_amdgcn_mfma_f32_16x16x32_bf16(a2, bf1[j], acc[18 + j], 0, 0, 0);
                    acc[27 + j] = __builtin_amdgcn_mfma_f32_16x16x32_bf16(a3, bf1[j], acc[27 + j], 0, 0, 0);
                }
            }
        }

        // ---- cross-wave K reduction (3 barriers) ----
        auto stR = [&](int base) __attribute__((always_inline)) {
#pragma unroll
            for (int g = 0; g < 4; ++g)
#pragma unroll
                for (int j = 0; j < 9; ++j)
#pragma unroll
                    for (int r = 0; r < 4; ++r)
                        R[base + (g * 16 + quad * 4 + r) * LRF + j * 16 + l15] = acc[g * 9 + j][r];
        };
        auto ldR = [&](int base) __attribute__((always_inline)) {
#pragma unroll
            for (int g = 0; g < 4; ++g)
#pragma unroll
                for (int j = 0; j < 9; ++j)
#pragma unroll
                    for (int r = 0; r < 4; ++r)
                        acc[g * 9 + j][r] += R[base + (g * 16 + quad * 4 + r) * LRF + j * 16 + l15];
        };
        if (wave == 1) stR(0);
        if (wave == 3) stR(64 * LRF);
        __syncthreads();
        if (wave == 0) ldR(0);
        if (wave == 2) ldR(64 * LRF);
        __syncthreads();
        if (wave == 2) stR(0);
        __syncthreads();

        // ---- epilogue (wave 0 only; no early return so reps stay barrier-safe) ----
        if (wave == 0) {
            ldR(0);
            float mul[4][4];
            if constexpr (MODE != 0) {
#pragma unroll
                for (int g = 0; g < 4; ++g)
#pragma unroll
                    for (int r = 0; r < 4; ++r) {
                        float sv = __shfl(acc[g * 9 + 8][r], lane & 48);  // lane quad*16 holds col 128
                        mul[g][r] = (sv > 0.f) ? 1.f / sv : 0.f;
                    }
            }
#pragma unroll
            for (int g = 0; g < 4; ++g) {
                const int row = m0 + g * 16 + quad * 4;
                if constexpr (MODE == 2) {
                    float* op = outF + ((size_t)batch * N_ + row) * C_;
#pragma unroll
                    for (int j = 0; j < 8; ++j) {
                        int c = j * 16 + l15;
#pragma unroll
                        for (int r = 0; r < 4; ++r) op[(size_t)r * C_ + c] = acc[g * 9 + j][r] * mul[g][r];
                    }
                } else {
#pragma unroll
                    for (int j = 0; j < 8; ++j) {
                        int c = j * 16 + l15;
                        float v0, v1, v2, v3;
                        if constexpr (MODE == 0) {
                            float bb = bias[c];
                            v0 = acc[g * 9 + j][0] + bb; v1 = acc[g * 9 + j][1] + bb;
                            v2 = acc[g * 9 + j][2] + bb; v3 = acc[g * 9 + j][3] + bb;
                        } else {
                            v0 = acc[g * 9 + j][0] * mul[g][0]; v1 = acc[g * 9 + j][1] * mul[g][1];
                            v2 = acc[g * 9 + j][2] * mul[g][2]; v3 = acc[g * 9 + j][3] * mul[g][3];
                        }
                        uint32_t q0 = (uint32_t)bf16_rne(v0) | ((uint32_t)bf16_rne(v1) << 16);
                        uint32_t q1 = (uint32_t)bf16_rne(v2) | ((uint32_t)bf16_rne(v3) << 16);
                        uint16_t* op = outT + ((size_t)batch * CN + c) * OLD + row;
                        *(uint2*)op = make_uint2(q0, q1);
                    }
                }
            }
        }
        __syncthreads();   // protect R before next rep's stR (no-op on last rep)
    }
}

// ---------------------------------------------------------------------------
extern "C" void kernel_launch(void* const* d_in, const int* in_sizes, int n_in,
                              void* d_out, int out_size, void* d_ws, size_t ws_size,
                              hipStream_t stream) {
    const float* x    = (const float*)d_in[0];   // [8,4096,128]
    const float* H    = (const float*)d_in[1];   // [8,4096,2048]
    const float* W    = (const float*)d_in[2];   // [128,128]
    const float* bias = (const float*)d_in[3];   // [128]
    float* out = (float*)d_out;                  // [8,4096,128]

    // ws (~12.8 MB): HT (8 MB) | WTb (36 KB) | ebfT (4.7 MB)
    uint32_t* HT   = (uint32_t*)d_ws;
    uint16_t* WTb  = (uint16_t*)(HT + HT_E);
    uint16_t* ebfT = WTb + WT_E;
    uint16_t* xwbT = (uint16_t*)d_out;           // d_out is dead scratch until e2v

    pack_kernel<<<dim3(8192), dim3(256), 0, stream>>>(H, HT);
    prep_kernel<<<dim3(1024), dim3(256), 0, stream>>>(W, WTb, (uint32_t*)xwbT, (uint32_t*)ebfT);
    gemm_k<0, 1><<<dim3(8 * (N_ / MT)), dim3(256), 0, stream>>>(x, nullptr, WTb, bias, xwbT, nullptr);
    gemm_k<1, 4><<<dim3(8 * (E_ / MT)), dim3(256), 0, stream>>>(nullptr, HT, xwbT, nullptr, ebfT, nullptr);
    gemm_k<2, 4><<<dim3(8 * (N_ / MT)), dim3(256), 0, stream>>>(nullptr, HT, ebfT, nullptr, nullptr, out);
}

// Round 3
// 484.245 us; speedup vs baseline: 1.9740x; 1.9740x over previous
//
#include <hip/hip_runtime.h>
#include <stdint.h>

// Problem constants
constexpr int B_ = 8, N_ = 4096, E_ = 2048, C_ = 128;
constexpr int KT  = 32;    // K per MFMA step
constexpr int MT  = 64;    // M rows per block (4 x 16-row groups, all owned by every wave)
constexpr int NWK = 4;     // K-split across the 4 waves of a block
constexpr int NJ  = C_ / 16;  // 8 col-tiles (ones-col removed; scales precomputed)
constexpr int LRF = 132;   // reduction LDS row stride (floats)

typedef short bf16x8 __attribute__((ext_vector_type(8)));
typedef float f32x4  __attribute__((ext_vector_type(4)));

__device__ inline uint16_t bf16_rne(float f) {
    uint32_t u = __builtin_bit_cast(uint32_t, f);
    return (uint16_t)((u + 0x7FFFu + ((u >> 16) & 1u)) >> 16);
}

__device__ __attribute__((always_inline)) inline void glds16(const void* g, void* l) {
    // global -> LDS direct, 16B/lane; LDS dest = wave-uniform base + lane*16
    __builtin_amdgcn_global_load_lds(
        (const __attribute__((address_space(1))) uint32_t*)g,
        (__attribute__((address_space(3))) uint32_t*)l, 16, 0, 0);
}

constexpr size_t HT_E  = (size_t)B_ * (N_ / 32) * E_;  // 2M dwords = 8 MB
constexpr size_t WT_E  = (size_t)C_ * C_;              // 16384 bf16
constexpr size_t EBF_E = (size_t)B_ * C_ * E_;         // 2M bf16 = 4 MB
constexpr size_t RS_E  = (size_t)B_ * E_;              // 16K floats
constexpr size_t RD_E  = (size_t)B_ * N_;              // 32K floats

// ---------------------------------------------------------------------------
// pack: H (fp32 0/1) -> HT[b][n/32][e], bit i of word = H[b][32*(n/32)+i][e].
// HBM-bound: reads the irreducible 268 MB once.
// ---------------------------------------------------------------------------
__global__ void pack_kernel(const float* __restrict__ H, uint32_t* __restrict__ HT) {
    const int t  = threadIdx.x;
    const int eg = blockIdx.x & 7;
    const int ng = (blockIdx.x >> 3) & 127;
    const int b  = blockIdx.x >> 10;
    const int e  = eg * 256 + t;
    const float* hp = H + ((size_t)b * N_ + ng * 32) * E_ + e;
    uint32_t w = 0;
#pragma unroll
    for (int i = 0; i < 32; ++i) w |= (hp[(size_t)i * E_] > 0.5f) ? (1u << i) : 0u;
    HT[((size_t)b * (N_ / 32) + ng) * E_ + e] = w;
}

// ---------------------------------------------------------------------------
// prep: three jobs, one kernel (384 blocks x 256):
//  blocks [0,256)   : rd_n[b][n] = 1/deg(node n)  via per-bit ballot over HT rows
//  blocks [256,320) : rs_e[b][e] = 1/deg(edge e)  via popcount over HT columns
//  blocks [320,384) : WTb[c*128+k] = bf16(W[k][c])   (B-panel for fc)
// Exact integer degrees -> identical numerics to the old ones-column path.
// ---------------------------------------------------------------------------
__global__ void prep_kernel(const float* __restrict__ W, const uint32_t* __restrict__ HT,
                            uint16_t* __restrict__ WTb, float* __restrict__ rs_e,
                            float* __restrict__ rd_n) {
    const int blk = blockIdx.x, t = threadIdx.x;
    if (blk < 256) {
        const int wave = t >> 6, lane = t & 63;
        const int wid  = blk * 4 + wave;          // 0..1023 = (b, ng)
        const int b = wid >> 7, ng = wid & 127;
        const uint32_t* p = HT + ((size_t)b * (N_ / 32) + ng) * E_;
        int cnt = 0;
#pragma unroll 1
        for (int c8 = 0; c8 < E_ / 64; ++c8) {
            const uint32_t w = p[c8 * 64 + lane];
#pragma unroll
            for (int i = 0; i < 32; ++i) {
                unsigned long long m = __ballot((w >> i) & 1u);
                if (lane == i) cnt += __popcll(m);
            }
        }
        if (lane < 32)
            rd_n[(size_t)b * N_ + ng * 32 + lane] = (cnt > 0) ? 1.f / (float)cnt : 0.f;
    } else if (blk < 320) {
        const int i = (blk - 256) * 256 + t;      // 0..16383 = (b, e)
        const int b = i >> 11, e = i & 2047;
        const uint32_t* p = HT + (size_t)b * (N_ / 32) * E_ + e;
        int s = 0;
#pragma unroll 1
        for (int ng = 0; ng < N_ / 32; ++ng) s += __popc(p[(size_t)ng * E_]);
        rs_e[i] = (s > 0) ? 1.f / (float)s : 0.f;
    } else {
        const int i = (blk - 320) * 256 + t;      // 0..16383 = c*128+k
        const int c = i >> 7, k = i & 127;
        WTb[i] = bf16_rne(W[k * C_ + c]);
    }
}

// ---------------------------------------------------------------------------
// MFMA GEMM, MT=64, K-split across 4 waves. B staged in per-wave-PRIVATE LDS
// double-buffers via global_load_lds (no VGPR B-buffer -> no spill; round-2
// PMC showed 410 MB/dispatch scratch writes, MfmaUtil 9.4%). Main loop has
// ZERO barriers: per-wave tiles, counted s_waitcnt vmcnt(12) (2-step prefetch
// lead), lgkmcnt(0) fence before re-issuing into the just-read buffer.
// Reduction LDS aliases the B-tiles (barrier before reuse).
//  MODE 0 (fc) : A = x fp32,    B = WTb,  out bf16 C^T xwbT (+bias)
//  MODE 1 (v2e): A = H^T bits,  B = xwbT, out bf16 C^T ebfT (x rs_e)
//  MODE 2 (e2v): A = H bits,    B = ebfT, out fp32 row-major (x rd_n)
// ---------------------------------------------------------------------------

#define LOADA(S, k0_) do {                                                            \
    if constexpr (MODE == 0) {                                                        \
        _Pragma("unroll")                                                             \
        for (int g = 0; g < 4; ++g) {                                                 \
            const float* ap = Ax + ((size_t)batch * N_ + m0 + g * 16 + l15) * C_ + (k0_) + quad * 8; \
            const float4 f0 = *(const float4*)ap;                                     \
            const float4 f1 = *(const float4*)(ap + 4);                               \
            af##S[g*8+0]=f0.x; af##S[g*8+1]=f0.y; af##S[g*8+2]=f0.z; af##S[g*8+3]=f0.w; \
            af##S[g*8+4]=f1.x; af##S[g*8+5]=f1.y; af##S[g*8+6]=f1.z; af##S[g*8+7]=f1.w; \
        }                                                                             \
    } else if constexpr (MODE == 1) {                                                 \
        const uint32_t* p = Hp + (size_t)((k0_) >> 5) * E_ + m0 + l15;                \
        aw##S[0] = p[0]; aw##S[1] = p[16]; aw##S[2] = p[32]; aw##S[3] = p[48];        \
    } else {                                                                          \
        const uint32_t* p = Hp + (size_t)(m0 >> 5) * E_ + (k0_) + quad * 8;           \
        axl##S[0] = *(const uint4*)p;        axh##S[0] = *(const uint4*)(p + 4);      \
        axl##S[1] = *(const uint4*)(p + E_); axh##S[1] = *(const uint4*)(p + E_ + 4); \
    } } while (0)

#define MKFRAGS(S, a0, a1, a2, a3)                                                    \
    bf16x8 a0, a1, a2, a3;                                                            \
    do {                                                                              \
    if constexpr (MODE == 0) {                                                        \
        _Pragma("unroll")                                                             \
        for (int g = 0; g < 4; ++g) {                                                 \
            bf16x8 v;                                                                 \
            _Pragma("unroll")                                                         \
            for (int jj = 0; jj < 8; ++jj) v[jj] = (short)bf16_rne(af##S[g*8+jj]);    \
            ((g==0)?a0:(g==1)?a1:(g==2)?a2:a3) = v;                                   \
        }                                                                             \
    } else if constexpr (MODE == 1) {                                                 \
        _Pragma("unroll")                                                             \
        for (int g = 0; g < 4; ++g) {                                                 \
            const uint32_t w = aw##S[g];                                              \
            bf16x8 v;                                                                 \
            _Pragma("unroll")                                                         \
            for (int jj = 0; jj < 8; ++jj)                                            \
                v[jj] = (short)(((w >> (quad * 8 + jj)) & 1u) ? 0x3F80 : 0);          \
            ((g==0)?a0:(g==1)?a1:(g==2)?a2:a3) = v;                                   \
        }                                                                             \
    } else {                                                                          \
        _Pragma("unroll")                                                             \
        for (int g = 0; g < 4; ++g) {                                                 \
            const int row = g >> 1, bit = (g & 1) * 16 + l15;                         \
            const uint32_t u[8] = {axl##S[row].x, axl##S[row].y, axl##S[row].z, axl##S[row].w, \
                                   axh##S[row].x, axh##S[row].y, axh##S[row].z, axh##S[row].w}; \
            bf16x8 v;                                                                 \
            _Pragma("unroll")                                                         \
            for (int jj = 0; jj < 8; ++jj)                                            \
                v[jj] = (short)(((u[jj] >> bit) & 1u) ? 0x3F80 : 0);                  \
            ((g==0)?a0:(g==1)?a1:(g==2)?a2:a3) = v;                                   \
        }                                                                             \
    } } while (0)

template <int MODE>
__global__ __launch_bounds__(256, 2)
void gemm_k(const float* __restrict__ Ax, const uint32_t* __restrict__ HT,
            const uint16_t* __restrict__ Btb, const float* __restrict__ bias,
            const float* __restrict__ rcp, uint16_t* __restrict__ outT,
            float* __restrict__ outF) {
    constexpr int K  = (MODE == 0) ? C_ : (MODE == 1) ? N_ : E_;
    constexpr int KW = K / NWK;                 // per-wave K chunk
    constexpr int SW = KW / KT;                 // 1 / 32 / 16 steps
    constexpr int OLD = (MODE == 0) ? N_ : E_;  // outT inner length
    constexpr int RL  = (MODE == 1) ? E_ : N_;  // rcp stride

    // 67584 B: [0,65536) = 4 waves x 2 bufs x 8KB B-tiles (main loop);
    // whole range = 2 x 64x132 f32 reduction regions (after barrier).
    __shared__ __align__(16) uint8_t smem[2 * 64 * LRF * 4];

    const int t = threadIdx.x, wave = t >> 6, lane = t & 63;
    const int l15 = lane & 15, quad = lane >> 4;
    const int batch = blockIdx.x & 7;           // batch -> XCD: panel stays in one L2
    const int m0 = (blockIdx.x >> 3) * MT;
    const int kwv = wave * KW;

    const uint16_t* Bp = Btb + (MODE == 0 ? (size_t)0 : (size_t)batch * C_ * K);
    const uint32_t* Hp = HT + (size_t)batch * (N_ / 32) * E_;
    float* R = (float*)smem;
    uint8_t* myB = smem + wave * 16384;

    f32x4 acc[32];
#pragma unroll
    for (int i = 0; i < 32; ++i) acc[i] = (f32x4){0.f, 0.f, 0.f, 0.f};

    // A double-buffer: two statically-named register sets (rule: no runtime idx)
    float    af0[32], af1[32];
    uint32_t aw0[4], aw1[4];
    uint4    axl0[2], axh0[2], axl1[2], axh1[2];
    bf16x8   bfr[NJ];

    auto issueB = [&](int k0, int p) __attribute__((always_inline)) {
        uint8_t* dst = myB + p * 8192;
#pragma unroll
        for (int j = 0; j < NJ; ++j)
            glds16(&Bp[(size_t)(j * 16 + l15) * K + k0 + quad * 8], dst + j * 1024);
    };
    auto readB = [&](int p) __attribute__((always_inline)) {
        const uint8_t* src = myB + p * 8192 + lane * 16;
#pragma unroll
        for (int j = 0; j < NJ; ++j)
            bfr[j] = *(const bf16x8*)(src + j * 1024);
    };
    auto mfma_all = [&](bf16x8 a0, bf16x8 a1, bf16x8 a2, bf16x8 a3)
        __attribute__((always_inline)) {
#pragma unroll
        for (int j = 0; j < NJ; ++j) {
            acc[j]      = __builtin_amdgcn_mfma_f32_16x16x32_bf16(a0, bfr[j], acc[j],      0, 0, 0);
            acc[8 + j]  = __builtin_amdgcn_mfma_f32_16x16x32_bf16(a1, bfr[j], acc[8 + j],  0, 0, 0);
            acc[16 + j] = __builtin_amdgcn_mfma_f32_16x16x32_bf16(a2, bfr[j], acc[16 + j], 0, 0, 0);
            acc[24 + j] = __builtin_amdgcn_mfma_f32_16x16x32_bf16(a3, bfr[j], acc[24 + j], 0, 0, 0);
        }
    };
    auto wait_vm = [&](bool last) __attribute__((always_inline)) {
        // steady state: 12 younger ops in flight (4 A-loads + 8 B-glds for s+1)
        if (last) asm volatile("s_waitcnt vmcnt(0)" ::: "memory");
        else      asm volatile("s_waitcnt vmcnt(12)" ::: "memory");
    };

    // prologue: A(0),B(0) then A(1),B(1)
    LOADA(0, kwv);
    issueB(kwv, 0);
    if constexpr (SW > 1) { LOADA(1, kwv + KT); issueB(kwv + KT, 1); }

#pragma unroll 1
    for (int s = 0; s < SW; s += 2) {
        {   // even step: set0 / buf0
            wait_vm(SW == 1 || s == SW - 1);
            readB(0);
            MKFRAGS(0, a0, a1, a2, a3);
            asm volatile("s_waitcnt lgkmcnt(0)" ::: "memory");  // buf0 reads drained
            if (s + 2 < SW) { LOADA(0, kwv + (s + 2) * KT); issueB(kwv + (s + 2) * KT, 0); }
            mfma_all(a0, a1, a2, a3);
        }
        if (s + 1 < SW) {  // odd step: set1 / buf1
            wait_vm(s + 1 == SW - 1);
            readB(1);
            MKFRAGS(1, a0, a1, a2, a3);
            asm volatile("s_waitcnt lgkmcnt(0)" ::: "memory");  // buf1 reads drained
            if (s + 3 < SW) { LOADA(1, kwv + (s + 3) * KT); issueB(kwv + (s + 3) * KT, 1); }
            mfma_all(a0, a1, a2, a3);
        }
    }

    // ---- cross-wave K reduction (R aliases B-tiles -> barrier first) ----
    auto stR = [&](int base) __attribute__((always_inline)) {
#pragma unroll
        for (int g = 0; g < 4; ++g)
#pragma unroll
            for (int j = 0; j < NJ; ++j)
#pragma unroll
                for (int r = 0; r < 4; ++r)
                    R[base + (g * 16 + quad * 4 + r) * LRF + j * 16 + l15] = acc[g * 8 + j][r];
    };
    auto ldR = [&](int base) __attribute__((always_inline)) {
#pragma unroll
        for (int g = 0; g < 4; ++g)
#pragma unroll
            for (int j = 0; j < NJ; ++j)
#pragma unroll
                for (int r = 0; r < 4; ++r)
                    acc[g * 8 + j][r] += R[base + (g * 16 + quad * 4 + r) * LRF + j * 16 + l15];
    };
    __syncthreads();
    if (wave == 1) stR(0);
    if (wave == 3) stR(64 * LRF);
    __syncthreads();
    if (wave == 0) ldR(0);
    if (wave == 2) ldR(64 * LRF);
    __syncthreads();
    if (wave == 2) stR(0);
    __syncthreads();
    if (wave != 0) return;
    ldR(0);

    // ---- epilogue (wave 0) ----
    float mul[4][4];
    if constexpr (MODE != 0) {
#pragma unroll
        for (int g = 0; g < 4; ++g) {
            const float4 rv = *(const float4*)&rcp[(size_t)batch * RL + m0 + g * 16 + quad * 4];
            mul[g][0] = rv.x; mul[g][1] = rv.y; mul[g][2] = rv.z; mul[g][3] = rv.w;
        }
    }
#pragma unroll
    for (int g = 0; g < 4; ++g) {
        const int row = m0 + g * 16 + quad * 4;
        if constexpr (MODE == 2) {
            float* op = outF + ((size_t)batch * N_ + row) * C_;
#pragma unroll
            for (int j = 0; j < NJ; ++j) {
                int c = j * 16 + l15;
#pragma unroll
                for (int r = 0; r < 4; ++r) op[(size_t)r * C_ + c] = acc[g * 8 + j][r] * mul[g][r];
            }
        } else {
#pragma unroll
            for (int j = 0; j < NJ; ++j) {
                int c = j * 16 + l15;
                float v0, v1, v2, v3;
                if constexpr (MODE == 0) {
                    float bb = bias[c];
                    v0 = acc[g * 8 + j][0] + bb; v1 = acc[g * 8 + j][1] + bb;
                    v2 = acc[g * 8 + j][2] + bb; v3 = acc[g * 8 + j][3] + bb;
                } else {
                    v0 = acc[g * 8 + j][0] * mul[g][0]; v1 = acc[g * 8 + j][1] * mul[g][1];
                    v2 = acc[g * 8 + j][2] * mul[g][2]; v3 = acc[g * 8 + j][3] * mul[g][3];
                }
                uint32_t q0 = (uint32_t)bf16_rne(v0) | ((uint32_t)bf16_rne(v1) << 16);
                uint32_t q1 = (uint32_t)bf16_rne(v2) | ((uint32_t)bf16_rne(v3) << 16);
                uint16_t* op = outT + ((size_t)batch * C_ + c) * OLD + row;
                *(uint2*)op = make_uint2(q0, q1);
            }
        }
    }
}

// ---------------------------------------------------------------------------
extern "C" void kernel_launch(void* const* d_in, const int* in_sizes, int n_in,
                              void* d_out, int out_size, void* d_ws, size_t ws_size,
                              hipStream_t stream) {
    const float* x    = (const float*)d_in[0];   // [8,4096,128]
    const float* H    = (const float*)d_in[1];   // [8,4096,2048]
    const float* W    = (const float*)d_in[2];   // [128,128]
    const float* bias = (const float*)d_in[3];   // [128]
    float* out = (float*)d_out;                  // [8,4096,128]

    // ws (~12.3 MB): HT 8MB | WTb 32KB | ebfT 4MB | rs_e 64KB | rd_n 128KB
    uint32_t* HT   = (uint32_t*)d_ws;
    uint16_t* WTb  = (uint16_t*)(HT + HT_E);
    uint16_t* ebfT = WTb + WT_E;
    float*    rs_e = (float*)(ebfT + EBF_E);
    float*    rd_n = rs_e + RS_E;
    uint16_t* xwbT = (uint16_t*)d_out;           // d_out is dead scratch until e2v

    pack_kernel<<<dim3(8192), dim3(256), 0, stream>>>(H, HT);
    prep_kernel<<<dim3(384), dim3(256), 0, stream>>>(W, HT, WTb, rs_e, rd_n);
    gemm_k<0><<<dim3(8 * (N_ / MT)), dim3(256), 0, stream>>>(x, nullptr, WTb, bias, nullptr, xwbT, nullptr);
    gemm_k<1><<<dim3(8 * (E_ / MT)), dim3(256), 0, stream>>>(nullptr, HT, xwbT, nullptr, rs_e, ebfT, nullptr);
    gemm_k<2><<<dim3(8 * (N_ / MT)), dim3(256), 0, stream>>>(nullptr, HT, ebfT, nullptr, rd_n, nullptr, out);
}